// Round 6
// baseline (1016.443 us; speedup 1.0000x reference)
//
#include <hip/hip_runtime.h>

typedef __bf16 bf16;
typedef __attribute__((ext_vector_type(8))) __bf16 bf16x8;
typedef __attribute__((ext_vector_type(4))) __bf16 bf16x4;
typedef __attribute__((ext_vector_type(4))) float f32x4;
typedef __attribute__((ext_vector_type(4))) short s16x4;

#define SCALE 0.17677669529663687f   // 1/sqrt(32)

// compiler fence between phases: stops cross-phase load hoisting / CSE that
// exploded live ranges in rounds 3-4 (scratch spill)
#define PHASE_FENCE() asm volatile("" ::: "memory")

// xs row stride: 536 bf16 = 1072 B = 268 dw == 12 (mod 32 banks) -> the
// 16-row A-frag walk maps to ~2-way bank aliasing (free) instead of the
// ~8-way seen with 520 (29M conflict-cycles in r5). 16B aligned.
#define XS_LD 536

__device__ __forceinline__ f32x4 mfma16(bf16x8 a, bf16x8 b, f32x4 c) {
  return __builtin_amdgcn_mfma_f32_16x16x32_bf16(a, b, c, 0, 0, 0);
}

// K=16 bf16 MFMA. Layouts (HW-verified rounds 1-5):
//   A: lane holds A[m=l15][k=quad*4+j]   B: lane holds B[k=quad*4+j][n=l15]
//   C: lane holds C[row=quad*4+r][col=l15]
__device__ __forceinline__ f32x4 mfma16k16(bf16x4 a, bf16x4 b, f32x4 c) {
#if __has_builtin(__builtin_amdgcn_mfma_f32_16x16x16bf16_1k)
  return __builtin_amdgcn_mfma_f32_16x16x16bf16_1k(
      __builtin_bit_cast(s16x4, a), __builtin_bit_cast(s16x4, b), c, 0, 0, 0);
#else
  asm("v_mfma_f32_16x16x16_bf16 %0, %1, %2, %0" : "+v"(c) : "v"(a), "v"(b));
  return c;
#endif
}

// ---------------------------------------------------------------------------
// prep: wt[c][k] = bf16(w_qkv[k][c])  (512x1536 -> 1536x512, row-major in k)
//       wpt[c][k] = bf16(w_proj[k][c]) (512x512)
// ---------------------------------------------------------------------------
__global__ void prep_weights(const float* __restrict__ w_qkv,
                             const float* __restrict__ w_proj,
                             bf16* __restrict__ wt, bf16* __restrict__ wpt) {
  __shared__ float tile[32][33];
  int b = blockIdx.x;
  const float* src; bf16* dst; int C, tk, tc;
  if (b < 768) {            // 16 k-tiles x 48 c-tiles
    src = w_qkv; dst = wt; C = 1536; tk = (b & 15) * 32; tc = (b >> 4) * 32;
  } else {                  // 16 x 16 tiles
    b -= 768; src = w_proj; dst = wpt; C = 512; tk = (b & 15) * 32; tc = (b >> 4) * 32;
  }
  int tx = threadIdx.x & 31, ty = threadIdx.x >> 5;
#pragma unroll
  for (int i = 0; i < 4; i++)
    tile[ty + i * 8][tx] = src[(size_t)(tk + ty + i * 8) * C + tc + tx];
  __syncthreads();
#pragma unroll
  for (int i = 0; i < 4; i++)
    dst[(size_t)(tc + ty + i * 8) * 512 + tk + tx] = (bf16)tile[tx][ty + i * 8];
}

// ---------------------------------------------------------------------------
// Kernel A: attention up to ao (= concat of head outputs), NO out-proj.
// Block = 512 threads = 8 waves = 8 heads of one window (2 blocks per window).
// ONE barrier (xs staging); afterwards every wave runs a fully private
// pipeline and exits -> no lockstep, 2 co-resident blocks/CU stagger.
// ao (bf16) is written into the upper 64KB of each 64-row block-range of
// `out`, so the oproj kernel is race-free under any dispatch order:
//   block m of oproj reads bytes [m*131072+65536, m*131072+131072) (its ao)
//   and writes bytes [m*131072, m*131072+131072) (its out rows) only.
// ---------------------------------------------------------------------------
__launch_bounds__(512, 4)
__global__ void ewattn_a(const float* __restrict__ x,
                         const float* __restrict__ b_qkv,
                         const float* __restrict__ w_k,
                         const float* __restrict__ w_v,
                         const float* __restrict__ bias_table,
                         const bf16* __restrict__ wt,
                         float* out) {
  __shared__ bf16 xs[64][XS_LD];    // bf16(x) for this window

  const int tid  = threadIdx.x;
  const int lane = tid & 63;
  const int wid  = tid >> 6;
  const int l15  = lane & 15;
  const int quad = lane >> 4;
  const int win  = blockIdx.x >> 1;
  const int h    = (blockIdx.x & 1) * 8 + wid;   // this wave's head
  const float* xw = x + (size_t)win * (64 * 512);

  // ---------------- stage x -> LDS (bf16); the only barrier ----------------
#pragma unroll
  for (int j = 0; j < 8; j++) {
    int i = tid + j * 512;
    int r = i >> 6, c8 = (i & 63) * 8;
    float4 v0 = *reinterpret_cast<const float4*>(xw + r * 512 + c8);
    float4 v1 = *reinterpret_cast<const float4*>(xw + r * 512 + c8 + 4);
    bf16x8 p;
    p[0] = (bf16)v0.x; p[1] = (bf16)v0.y; p[2] = (bf16)v0.z; p[3] = (bf16)v0.w;
    p[4] = (bf16)v1.x; p[5] = (bf16)v1.y; p[6] = (bf16)v1.z; p[7] = (bf16)v1.w;
    *reinterpret_cast<bf16x8*>(&xs[r][c8]) = p;
  }
  __syncthreads();

  // ---- K pass: k = x @ Wk + b_k ----
  bf16x4 kb[4][2];
  {
    f32x4 kacc[4][2];
#pragma unroll
    for (int tt = 0; tt < 4; tt++)
#pragma unroll
      for (int nt = 0; nt < 2; nt++) kacc[tt][nt] = f32x4{0.f,0.f,0.f,0.f};
    for (int kt = 0; kt < 16; kt++) {
      bf16x8 af[4];
#pragma unroll
      for (int tt = 0; tt < 4; tt++)
        af[tt] = *(const bf16x8*)&xs[tt * 16 + l15][kt * 32 + quad * 8];
      bf16x8 bwk[2];
#pragma unroll
      for (int nt = 0; nt < 2; nt++)
        bwk[nt] = *(const bf16x8*)&wt[(size_t)(512 + h * 32 + nt * 16 + l15) * 512 + kt * 32 + quad * 8];
#pragma unroll
      for (int tt = 0; tt < 4; tt++)
#pragma unroll
        for (int nt = 0; nt < 2; nt++)
          kacc[tt][nt] = mfma16(af[tt], bwk[nt], kacc[tt][nt]);
    }
#pragma unroll
    for (int nt = 0; nt < 2; nt++) {
      float bk = b_qkv[512 + h * 32 + nt * 16 + l15];
#pragma unroll
      for (int tt = 0; tt < 4; tt++)
#pragma unroll
        for (int r = 0; r < 4; r++)
          kb[tt][nt][r] = (bf16)(kacc[tt][nt][r] + bk);
    }
  }
  PHASE_FENCE();

  // ---- V pass: v = x @ Wv + b_v ----
  bf16x4 vb[4][2];
  {
    f32x4 vacc[4][2];
#pragma unroll
    for (int tt = 0; tt < 4; tt++)
#pragma unroll
      for (int nt = 0; nt < 2; nt++) vacc[tt][nt] = f32x4{0.f,0.f,0.f,0.f};
    for (int kt = 0; kt < 16; kt++) {
      bf16x8 af[4];
#pragma unroll
      for (int tt = 0; tt < 4; tt++)
        af[tt] = *(const bf16x8*)&xs[tt * 16 + l15][kt * 32 + quad * 8];
      bf16x8 bwv[2];
#pragma unroll
      for (int nt = 0; nt < 2; nt++)
        bwv[nt] = *(const bf16x8*)&wt[(size_t)(1024 + h * 32 + nt * 16 + l15) * 512 + kt * 32 + quad * 8];
#pragma unroll
      for (int tt = 0; tt < 4; tt++)
#pragma unroll
        for (int nt = 0; nt < 2; nt++)
          vacc[tt][nt] = mfma16(af[tt], bwv[nt], vacc[tt][nt]);
    }
#pragma unroll
    for (int nt = 0; nt < 2; nt++) {
      float bv = b_qkv[1024 + h * 32 + nt * 16 + l15];
#pragma unroll
      for (int tt = 0; tt < 4; tt++)
#pragma unroll
        for (int r = 0; r < 4; r++)
          vb[tt][nt][r] = (bf16)(vacc[tt][nt][r] + bv);
    }
  }
  PHASE_FENCE();

  // ---- linformer proj: kpT = k^T @ w_k^T, vp = w_v @ v (K=16) ----
  bf16x4 kpf[2], vpf[2];
  {
    bf16x4 wkf[4], wvf[4];          // w[p=l15][tok=tt*16+quad*4+j], L1-hot
#pragma unroll
    for (int tt = 0; tt < 4; tt++) {
      float4 a = *(const float4*)&w_k[l15 * 64 + tt * 16 + quad * 4];
      float4 b = *(const float4*)&w_v[l15 * 64 + tt * 16 + quad * 4];
      wkf[tt][0] = (bf16)a.x; wkf[tt][1] = (bf16)a.y; wkf[tt][2] = (bf16)a.z; wkf[tt][3] = (bf16)a.w;
      wvf[tt][0] = (bf16)b.x; wvf[tt][1] = (bf16)b.y; wvf[tt][2] = (bf16)b.z; wvf[tt][3] = (bf16)b.w;
    }
    f32x4 kpacc[2], vpacc[2];
    kpacc[0] = kpacc[1] = vpacc[0] = vpacc[1] = f32x4{0.f,0.f,0.f,0.f};
#pragma unroll
    for (int tt = 0; tt < 4; tt++)
#pragma unroll
      for (int nt = 0; nt < 2; nt++) {
        kpacc[nt] = mfma16k16(kb[tt][nt], wkf[tt], kpacc[nt]);   // C lane=p, regs=d
        vpacc[nt] = mfma16k16(wvf[tt], vb[tt][nt], vpacc[nt]);   // C lane=d, regs=p
      }
#pragma unroll
    for (int nt = 0; nt < 2; nt++)
#pragma unroll
      for (int r = 0; r < 4; r++) {
        kpf[nt][r] = (bf16)kpacc[nt][r];
        vpf[nt][r] = (bf16)vpacc[nt][r];
      }
  }
  PHASE_FENCE();

  // ---- Q pass: qT = Wq^T @ x^T (C: lane=token, regs=channel) ----
  bf16x4 qb[2][4];
  {
    f32x4 qacc[2][4];
#pragma unroll
    for (int ct = 0; ct < 2; ct++)
#pragma unroll
      for (int tt = 0; tt < 4; tt++) qacc[ct][tt] = f32x4{0.f,0.f,0.f,0.f};
    for (int kt = 0; kt < 16; kt++) {
      bf16x8 aw[2];
#pragma unroll
      for (int ct = 0; ct < 2; ct++)
        aw[ct] = *(const bf16x8*)&wt[(size_t)(h * 32 + ct * 16 + l15) * 512 + kt * 32 + quad * 8];
      bf16x8 bx[4];
#pragma unroll
      for (int tt = 0; tt < 4; tt++)
        bx[tt] = *(const bf16x8*)&xs[tt * 16 + l15][kt * 32 + quad * 8];
#pragma unroll
      for (int ct = 0; ct < 2; ct++)
#pragma unroll
        for (int tt = 0; tt < 4; tt++)
          qacc[ct][tt] = mfma16(aw[ct], bx[tt], qacc[ct][tt]);
    }
#pragma unroll
    for (int ct = 0; ct < 2; ct++)
#pragma unroll
      for (int tt = 0; tt < 4; tt++)
#pragma unroll
        for (int r = 0; r < 4; r++)
          qb[ct][tt][r] = (bf16)((qacc[ct][tt][r] +
                                  b_qkv[h * 32 + ct * 16 + quad * 4 + r]) * SCALE);
  }
  PHASE_FENCE();

  // ---- QK^T + bias + softmax -> probs; PV; write ao to global ----
  bf16* aoW = reinterpret_cast<bf16*>(reinterpret_cast<char*>(out) +
                                      ((size_t)win * 131072 + 65536));
#pragma unroll
  for (int tt = 0; tt < 4; tt++) {
    f32x4 att = mfma16k16(kpf[0], qb[0][tt], f32x4{0.f,0.f,0.f,0.f});
    att = mfma16k16(kpf[1], qb[1][tt], att);
    int n = tt * 16 + l15;
    float e[4], s = 0.f;
#pragma unroll
    for (int r = 0; r < 4; r++) {
      int p = quad * 4 + r;
      int rel = ((n >> 3) - (p >> 3) + 7) * 15 + ((n & 7) - (p & 7) + 7);
      e[r] = __expf(att[r] + bias_table[rel * 16 + h]);
      s += e[r];
    }
    s += __shfl_xor(s, 16); s += __shfl_xor(s, 32);
    float rc = __builtin_amdgcn_rcpf(s);
    bf16x4 ap;
#pragma unroll
    for (int r = 0; r < 4; r++) ap[r] = (bf16)(e[r] * rc);
    // PV (K=16 exact): C row = token = quad*4+r (within this tt tile), col = d
#pragma unroll
    for (int nd = 0; nd < 2; nd++) {
      f32x4 ov = mfma16k16(ap, vpf[nd], f32x4{0.f,0.f,0.f,0.f});
#pragma unroll
      for (int r = 0; r < 4; r++) {
        int token = tt * 16 + quad * 4 + r;
        aoW[token * 512 + h * 32 + nd * 16 + l15] = (bf16)ov[r];
      }
    }
  }
}

// ---------------------------------------------------------------------------
// Kernel B: out = ao @ w_proj + b_proj.  Block m: 64 rows of ao/out.
// Reads its ao (upper half of its own 131072-byte range of `out`) into LDS,
// barrier, GEMM, writes its own rows -> in-place safe, dispatch-order safe.
// ---------------------------------------------------------------------------
__launch_bounds__(512, 4)
__global__ void oproj(const float* __restrict__ b_proj,
                      const bf16* __restrict__ wpt,
                      float* out) {
  __shared__ bf16 as_[64][XS_LD];

  const int tid  = threadIdx.x;
  const int lane = tid & 63;
  const int wid  = tid >> 6;
  const int l15  = lane & 15;
  const int quad = lane >> 4;
  const int mb   = blockIdx.x;      // 64-row block

  const bf16* aoR = reinterpret_cast<const bf16*>(reinterpret_cast<const char*>(out) +
                                                  ((size_t)mb * 131072 + 65536));
#pragma unroll
  for (int j = 0; j < 8; j++) {
    int i = tid + j * 512;
    int r = i >> 6, c8 = (i & 63) * 8;
    *reinterpret_cast<bf16x8*>(&as_[r][c8]) =
        *reinterpret_cast<const bf16x8*>(&aoR[r * 512 + c8]);
  }
  __syncthreads();

  f32x4 oacc[4][4];
#pragma unroll
  for (int mt = 0; mt < 4; mt++)
#pragma unroll
    for (int nt = 0; nt < 4; nt++) oacc[mt][nt] = f32x4{0.f,0.f,0.f,0.f};
  for (int kt = 0; kt < 16; kt++) {
    bf16x8 af[4];
#pragma unroll
    for (int mt = 0; mt < 4; mt++)
      af[mt] = *(const bf16x8*)&as_[mt * 16 + l15][kt * 32 + quad * 8];
    bf16x8 bw[4];
#pragma unroll
    for (int nt = 0; nt < 4; nt++)
      bw[nt] = *(const bf16x8*)&wpt[(size_t)(wid * 64 + nt * 16 + l15) * 512 + kt * 32 + quad * 8];
#pragma unroll
    for (int mt = 0; mt < 4; mt++)
#pragma unroll
      for (int nt = 0; nt < 4; nt++)
        oacc[mt][nt] = mfma16(af[mt], bw[nt], oacc[mt][nt]);
  }
  float* ow = out + (size_t)mb * (64 * 512);
#pragma unroll
  for (int nt = 0; nt < 4; nt++) {
    int c = wid * 64 + nt * 16 + l15;
    float bp = b_proj[c];
#pragma unroll
    for (int mt = 0; mt < 4; mt++)
#pragma unroll
      for (int r = 0; r < 4; r++)
        ow[(size_t)(mt * 16 + quad * 4 + r) * 512 + c] = oacc[mt][nt][r] + bp;
  }
}

extern "C" void kernel_launch(void* const* d_in, const int* in_sizes, int n_in,
                              void* d_out, int out_size, void* d_ws, size_t ws_size,
                              hipStream_t stream) {
  const float* x          = (const float*)d_in[0];
  const float* w_qkv      = (const float*)d_in[1];
  const float* b_qkv      = (const float*)d_in[2];
  const float* w_proj     = (const float*)d_in[3];
  const float* b_proj     = (const float*)d_in[4];
  const float* w_k        = (const float*)d_in[5];
  const float* w_v        = (const float*)d_in[6];
  const float* bias_table = (const float*)d_in[7];
  (void)in_sizes; (void)n_in; (void)out_size; (void)ws_size;

  bf16* wt  = (bf16*)d_ws;            // [1536][512]
  bf16* wpt = wt + 1536 * 512;        // [512][512]

  prep_weights<<<1024, 256, 0, stream>>>(w_qkv, w_proj, wt, wpt);
  ewattn_a<<<4096, 512, 0, stream>>>(x, b_qkv, w_k, w_v, bias_table,
                                     wt, (float*)d_out);
  oproj<<<2048, 512, 0, stream>>>(b_proj, wpt, (float*)d_out);
}